// Round 1
// baseline (273.846 us; speedup 1.0000x reference)
//
#include <hip/hip_runtime.h>

#define BATCH 64
#define TLEN 1000
#define F 128
#define S 10
#define L 100           // TLEN / S
#define NPAIR 8128      // F*(F-1)/2
#define NTILE 528       // (F/4)*(F/4+1)/2 lower-tri 4x4 tile grid incl. diagonal

__global__ __launch_bounds__(256) void corr_kernel(const float* __restrict__ x,
                                                   float* __restrict__ out) {
    const int win = blockIdx.x;          // 0 .. BATCH*L-1
    const int b = win / L;
    const int l = win % L;
    const int tid = threadIdx.x;

    __shared__ float ms[S][F];    // window, then mean-subtracted in place (5 KB)
    __shared__ float stdv[F];     // per-feature population std

    // ---- load window: 1280 floats = 320 float4, coalesced ----
    const float* src = x + ((size_t)b * TLEN + (size_t)l * S) * F;
    const float4* src4 = (const float4*)src;
    float4* lds4 = (float4*)&ms[0][0];
    for (int i = tid; i < (S * F) / 4; i += 256) {
        lds4[i] = src4[i];
    }
    __syncthreads();

    // ---- per-feature mean / center / std (threads 0..127, one column each) ----
    if (tid < F) {
        const int f = tid;
        float col[S];
        float sum = 0.f;
        #pragma unroll
        for (int s = 0; s < S; ++s) { col[s] = ms[s][f]; sum += col[s]; }
        const float mean = sum / (float)S;
        float sq = 0.f;
        #pragma unroll
        for (int s = 0; s < S; ++s) { float d = col[s] - mean; col[s] = d; sq += d * d; }
        #pragma unroll
        for (int s = 0; s < S; ++s) ms[s][f] = col[s];
        stdv[f] = sqrtf(sq / (float)S);
    }
    __syncthreads();

    float* outw = out + (size_t)win * NPAIR;

    // ---- lower-triangle correlation via 4x4 register tiles ----
    for (int t = tid; t < NTILE; t += 256) {
        // map linear tile index -> (ti, tj), ti >= tj, row-major lower triangle
        int ti = (int)((sqrtf(8.0f * (float)t + 1.0f) - 1.0f) * 0.5f);
        while ((ti + 1) * (ti + 2) / 2 <= t) ++ti;   // fix sqrt rounding
        while (ti * (ti + 1) / 2 > t) --ti;
        const int tj = t - ti * (ti + 1) / 2;

        float acc[4][4];
        #pragma unroll
        for (int a = 0; a < 4; ++a)
            #pragma unroll
            for (int c = 0; c < 4; ++c) acc[a][c] = 0.f;

        #pragma unroll
        for (int s = 0; s < S; ++s) {
            const float4 av = *(const float4*)&ms[s][ti * 4];
            const float4 bv = *(const float4*)&ms[s][tj * 4];
            const float a0[4] = {av.x, av.y, av.z, av.w};
            const float b0[4] = {bv.x, bv.y, bv.z, bv.w};
            #pragma unroll
            for (int di = 0; di < 4; ++di)
                #pragma unroll
                for (int dj = 0; dj < 4; ++dj)
                    acc[di][dj] += a0[di] * b0[dj];
        }

        float sa[4], sb[4];
        #pragma unroll
        for (int d = 0; d < 4; ++d) { sa[d] = stdv[ti * 4 + d]; sb[d] = stdv[tj * 4 + d]; }

        #pragma unroll
        for (int di = 0; di < 4; ++di) {
            const int i = ti * 4 + di;
            #pragma unroll
            for (int dj = 0; dj < 4; ++dj) {
                const int j = tj * 4 + dj;
                if (j < i) {
                    const float den = sa[di] * sb[dj];
                    const float cov = acc[di][dj] / (float)S;
                    outw[i * (i - 1) / 2 + j] = (den == 0.f) ? 0.f : cov / den;
                }
            }
        }
    }
}

extern "C" void kernel_launch(void* const* d_in, const int* in_sizes, int n_in,
                              void* d_out, int out_size, void* d_ws, size_t ws_size,
                              hipStream_t stream) {
    const float* x = (const float*)d_in[0];
    float* out = (float*)d_out;
    corr_kernel<<<BATCH * L, 256, 0, stream>>>(x, out);
}

// Round 3
// 252.394 us; speedup vs baseline: 1.0850x; 1.0850x over previous
//
#include <hip/hip_runtime.h>

#define BATCH 64
#define TLEN 1000
#define F 128
#define S 10
#define L 100           // TLEN / S
#define NPAIR 8128      // F*(F-1)/2
#define NTILE 528       // 32*33/2 lower-tri 4x4 tile grid incl. diagonal
#define NT4 (NPAIR / 4) // 2032 float4s per window
#define BLOCK 512

__global__ __launch_bounds__(BLOCK, 8) void corr_kernel(const float* __restrict__ x,
                                                        float* __restrict__ out) {
    const int win = blockIdx.x;          // 0 .. BATCH*L-1
    const int b = win / L;
    const int l = win % L;
    const int tid = threadIdx.x;

    __shared__ float ms[S][F];                   // window -> normalized deviations (5 KB)
    __shared__ __align__(16) float tri[NPAIR];   // packed lower triangle (32.5 KB)

    // ---- load window: 1280 floats = 320 float4, coalesced ----
    const float4* src4 = (const float4*)(x + ((size_t)b * TLEN + (size_t)l * S) * F);
    if (tid < (S * F) / 4) ((float4*)&ms[0][0])[tid] = src4[tid];
    __syncthreads();

    // ---- per-feature mean / center / normalize by rstd/sqrt(S) ----
    // corr[i][j] = sum_s (d_i * r_i)(d_j * r_j)  with  r = 1/(std*sqrt(S))
    // std==0  =>  all deviations 0  =>  column is 0  =>  output 0 (divide_no_nan)
    if (tid < F) {
        const int f = tid;
        float col[S];
        float sum = 0.f;
        #pragma unroll
        for (int s = 0; s < S; ++s) { col[s] = ms[s][f]; sum += col[s]; }
        const float mean = sum * (1.0f / S);
        float sq = 0.f;
        #pragma unroll
        for (int s = 0; s < S; ++s) { float d = col[s] - mean; col[s] = d; sq += d * d; }
        const float stdv = sqrtf(sq * (1.0f / S));
        const float r = (stdv == 0.f) ? 0.f : 0.31622776601683794f / stdv; // 1/(std*sqrt(10))
        #pragma unroll
        for (int s = 0; s < S; ++s) ms[s][f] = col[s] * r;
    }
    __syncthreads();

    // ---- lower-triangle 4x4 register tiles -> packed LDS triangle ----
    for (int t = tid; t < NTILE; t += BLOCK) {
        int ti = (int)((sqrtf(8.0f * (float)t + 1.0f) - 1.0f) * 0.5f);
        while ((ti + 1) * (ti + 2) / 2 <= t) ++ti;
        while (ti * (ti + 1) / 2 > t) --ti;
        const int tj = t - ti * (ti + 1) / 2;

        float acc[4][4];
        #pragma unroll
        for (int a = 0; a < 4; ++a)
            #pragma unroll
            for (int c = 0; c < 4; ++c) acc[a][c] = 0.f;

        #pragma unroll
        for (int s = 0; s < S; ++s) {
            const float4 av = *(const float4*)&ms[s][ti * 4];   // stride-16B across lanes / broadcast
            const float4 bv = *(const float4*)&ms[s][tj * 4];
            const float a0[4] = {av.x, av.y, av.z, av.w};
            const float b0[4] = {bv.x, bv.y, bv.z, bv.w};
            #pragma unroll
            for (int di = 0; di < 4; ++di)
                #pragma unroll
                for (int dj = 0; dj < 4; ++dj)
                    acc[di][dj] += a0[di] * b0[dj];
        }

        // scalar LDS writes; rotate dj by lane to break the stride-4 bank pattern
        #pragma unroll
        for (int di = 0; di < 4; ++di) {
            const int i = ti * 4 + di;
            const int rowoff = i * (i - 1) / 2 + tj * 4;
            #pragma unroll
            for (int k = 0; k < 4; ++k) {
                const int dj = (k + tid) & 3;
                const int j = tj * 4 + dj;
                if (j < i) tri[rowoff + dj] = acc[di][dj];
            }
        }
    }
    __syncthreads();

    // ---- flush: contiguous float4 LDS->global, fully coalesced ----
    const float4* t4 = (const float4*)tri;
    float4* o4 = (float4*)(out + (size_t)win * NPAIR);
    for (int p = tid; p < NT4; p += BLOCK) o4[p] = t4[p];
}

extern "C" void kernel_launch(void* const* d_in, const int* in_sizes, int n_in,
                              void* d_out, int out_size, void* d_ws, size_t ws_size,
                              hipStream_t stream) {
    const float* x = (const float*)d_in[0];
    float* out = (float*)d_out;
    corr_kernel<<<BATCH * L, BLOCK, 0, stream>>>(x, out);
}